// Round 1
// 262.245 us; speedup vs baseline: 1.0069x; 1.0069x over previous
//
#include <hip/hip_runtime.h>

// CostVolume2D: N=8, C=128, H=96, W=224, D=4 -> 81 channels.
// out[n, dy*9+dx, h, w] = mean_c f1[n,c,h,w] * f2[n,c,h+dy-4,w+dx-4] (0 if OOB)
//
// Round 5: latency pipeline fix. Round-4 counters showed all pipes idle
// (VALU 28%, HBM 22%, LDS ~27%) at ~2600 CU-cycles/channel vs ~600 issue-bound:
// __syncthreads() drains vmcnt(0) (m97 barrier-drain), so the 1-deep global
// prefetch was force-completed every iteration and all 3 waves convoyed on
// ~900cy HBM latency per channel. Changes (addresses/tiling/traffic identical):
//  (1) raw s_barrier + lgkmcnt(0)-only wait (no vmcnt drain at barriers; LDS is
//      the only cross-wave medium, global loads are register-destined).
//  (2) true 2-deep global prefetch: f2 granule + f1 pair for channel X issued
//      at iter X-2 (ping/pong regs), covering HBM latency.
//  (3) LDS frag reads pipelined 1 channel ahead: iter c reads frags(c+1)
//      (written before the PREVIOUS barrier) so ds_read latency hides under
//      the 72 FMAs. 2 buffers still race-free: reads of buf[p] at iter c are
//      drained by iter c's lgkmcnt(0)+barrier before buf[p] is rewritten at
//      iter c+1.
// Block = 192 threads (3 waves), tile 32(w) x 16(h). Wave wb handles
// dy = 3*dyg + wb. Per thread: 8w x 1h px x 9 dx = 72 fp32 accumulators.

constexpr int Cn = 128;
constexpr int Hh = 96;
constexpr int Ww = 224;
constexpr int HW = Hh * Ww;       // 21504
constexpr int TILE_H = 16;
constexpr int TILE_W = 32;
constexpr int F2R = 18;           // TILE_H + 2 (3 dy span)
constexpr int F2S = 44;           // row stride: pad 40->44 (read-conflict-free)
constexpr int CT  = F2R * F2S;    // 792 floats per channel tile

// Barrier with LDS-visibility drain ONLY. Global (vmcnt) loads stay in flight
// across the barrier; their consumers get compiler-inserted counted vmcnt(N).
__device__ __forceinline__ void sync_lgkm() {
    asm volatile("s_waitcnt lgkmcnt(0)" ::: "memory");
    __builtin_amdgcn_s_barrier();
    asm volatile("" ::: "memory");
}

__global__ __launch_bounds__(192, 3)
void costvol_kernel(const float* __restrict__ f1g, const float* __restrict__ f2g,
                    float* __restrict__ outg) {
    __shared__ float lds[2][CT];       // double buffer, 6336 B

    const int b    = blockIdx.x;
    const int xcd  = b & 7;            // consecutive block IDs round-robin XCDs
    const int j    = b >> 3;           // 0..125
    const int dyg  = j % 3;
    const int tp   = j / 3;            // 0..41
    const int tile = tp * 8 + xcd;     // same tile's 3 dy-groups -> same XCD
    const int wt   = tile % 7;
    const int ht   = (tile / 7) % 6;
    const int n    = tile / 42;

    const int h0 = ht * TILE_H;
    const int w0 = wt * TILE_W;
    const int d0 = dyg * 3;

    const int tid  = threadIdx.x;
    const int wb   = tid >> 6;         // wave id = dy offset in group
    const int lane = tid & 63;
    const int gx   = lane & 3;         // 8 w px: w = w0 + 8*gx + (0..7)
    const int gy   = lane >> 2;        // h row: h = h0 + gy

    // ---- staging: 180 float4 slots cover 18 rows x 10 groups ----
    const int  srow = tid / 10;
    const int  sg   = tid - srow * 10;
    const bool sAct = (tid < 180);
    const int  yS   = h0 + d0 - 4 + srow;
    const int  xS   = w0 - 4 + 4 * sg;        // float4 granule, never straddles W
    const bool sVal = sAct && (yS >= 0) && (yS < Hh) && (xS >= 0) && (xS < Ww);
    const int  sOff = sVal ? (yS * Ww + xS) : 0;
    const int  sLds = srow * F2S + 4 * sg;

    const size_t nbase = (size_t)n * Cn * HW;
    const float* f1n = f1g + nbase;
    const float* f2n = f2g + nbase;

    const int hA    = h0 + gy;
    const int wA    = w0 + 8 * gx;
    const int f1off = hA * Ww + wA;
    const int ldsr  = (gy + wb) * F2S + 8 * gx;

    const float* f2s = f2n + sOff;     // staging source base (valid iff sVal)
    const float* f1b = f1n + f1off;

    const float* ldr0 = &lds[0][ldsr];
    const float* ldr1 = &lds[1][ldsr];
    float*       ldw0 = &lds[0][sLds];
    float*       ldw1 = &lds[1][sLds];

    float4 acc[2][9];
#pragma unroll
    for (int p = 0; p < 2; ++p)
#pragma unroll
        for (int dx = 0; dx < 9; ++dx)
            acc[p][dx] = make_float4(0.f, 0.f, 0.f, 0.f);

    const float4 z4 = make_float4(0.f, 0.f, 0.f, 0.f);

    // ---- prologue: buffers for c=0,1; global pipeline primed 2 deep ----
    float4 stA = sVal ? *(const float4*)(f2s) : z4;            // f2(0)
    float4 stB = sVal ? *(const float4*)(f2s + HW) : z4;       // f2(1)
    float4 a0A = *(const float4*)(f1b);                        // f1(0)
    float4 a1A = *(const float4*)(f1b + 4);
    float4 a0B = *(const float4*)(f1b + HW);                   // f1(1)
    float4 a1B = *(const float4*)(f1b + HW + 4);

    if (sAct) *(float4*)(ldw0) = stA;
    sync_lgkm();

    float4 qA0 = *(const float4*)(ldr0);                       // frags(0)
    float4 qA1 = *(const float4*)(ldr0 + 4);
    float4 qA2 = *(const float4*)(ldr0 + 8);
    float4 qA3 = *(const float4*)(ldr0 + 12);
    if (sAct) *(float4*)(ldw1) = stB;                          // f2(1) -> buf1
    stA = sVal ? *(const float4*)(f2s + (size_t)2 * HW) : z4;  // f2(2)
    stB = sVal ? *(const float4*)(f2s + (size_t)3 * HW) : z4;  // f2(3)
    sync_lgkm();

    float4 qB0, qB1, qB2, qB3;

#pragma unroll 1
    for (int cc = 0; cc < Cn; cc += 2) {
        // ================= even channel c = cc =================
        {
            // frags(cc+1): written to buf1 before the LAST barrier -> latency
            // hides under this step's FMAs; drained at this step's barrier.
            qB0 = *(const float4*)(ldr1);
            qB1 = *(const float4*)(ldr1 + 4);
            qB2 = *(const float4*)(ldr1 + 8);
            qB3 = *(const float4*)(ldr1 + 12);
            if (sAct) *(float4*)(ldw0) = stA;                  // f2(cc+2)

            const float4 a0 = a0A, a1 = a1A;                   // f1(cc)
            const int cf2 = (cc + 4 < Cn) ? (cc + 4) : (Cn - 2);
            const int cf1 = (cc + 2 < Cn) ? (cc + 2) : (Cn - 2);
            stA = sVal ? *(const float4*)(f2s + (size_t)cf2 * HW) : z4;
            const float* f1p = f1b + (size_t)cf1 * HW;
            a0A = *(const float4*)(f1p);
            a1A = *(const float4*)(f1p + 4);

            const float wv[16] = {qA0.x, qA0.y, qA0.z, qA0.w,
                                  qA1.x, qA1.y, qA1.z, qA1.w,
                                  qA2.x, qA2.y, qA2.z, qA2.w,
                                  qA3.x, qA3.y, qA3.z, qA3.w};
#pragma unroll
            for (int dx = 0; dx < 9; ++dx) {
                acc[0][dx].x += a0.x * wv[dx + 0];
                acc[0][dx].y += a0.y * wv[dx + 1];
                acc[0][dx].z += a0.z * wv[dx + 2];
                acc[0][dx].w += a0.w * wv[dx + 3];
                acc[1][dx].x += a1.x * wv[dx + 4];
                acc[1][dx].y += a1.y * wv[dx + 5];
                acc[1][dx].z += a1.z * wv[dx + 6];
                acc[1][dx].w += a1.w * wv[dx + 7];
            }
            sync_lgkm();
        }
        // ================= odd channel c = cc+1 =================
        {
            qA0 = *(const float4*)(ldr0);                      // frags(cc+2)
            qA1 = *(const float4*)(ldr0 + 4);
            qA2 = *(const float4*)(ldr0 + 8);
            qA3 = *(const float4*)(ldr0 + 12);
            if (sAct) *(float4*)(ldw1) = stB;                  // f2(cc+3)

            const float4 a0 = a0B, a1 = a1B;                   // f1(cc+1)
            const int cf2 = (cc + 5 < Cn) ? (cc + 5) : (Cn - 1);
            const int cf1 = (cc + 3 < Cn) ? (cc + 3) : (Cn - 1);
            stB = sVal ? *(const float4*)(f2s + (size_t)cf2 * HW) : z4;
            const float* f1p = f1b + (size_t)cf1 * HW;
            a0B = *(const float4*)(f1p);
            a1B = *(const float4*)(f1p + 4);

            const float wv[16] = {qB0.x, qB0.y, qB0.z, qB0.w,
                                  qB1.x, qB1.y, qB1.z, qB1.w,
                                  qB2.x, qB2.y, qB2.z, qB2.w,
                                  qB3.x, qB3.y, qB3.z, qB3.w};
#pragma unroll
            for (int dx = 0; dx < 9; ++dx) {
                acc[0][dx].x += a0.x * wv[dx + 0];
                acc[0][dx].y += a0.y * wv[dx + 1];
                acc[0][dx].z += a0.z * wv[dx + 2];
                acc[0][dx].w += a0.w * wv[dx + 3];
                acc[1][dx].x += a1.x * wv[dx + 4];
                acc[1][dx].y += a1.y * wv[dx + 5];
                acc[1][dx].z += a1.z * wv[dx + 6];
                acc[1][dx].w += a1.w * wv[dx + 7];
            }
            sync_lgkm();
        }
    }

    // ---- writeout: 2 x 9 float4 per thread, coalesced 16B stores ----
    const float sc = 1.0f / 128.0f;
    const int dy = d0 + wb;
    float* ob = outg + (size_t)n * 81 * HW + (size_t)hA * Ww + wA;
#pragma unroll
    for (int dx = 0; dx < 9; ++dx) {
        const int k = dy * 9 + dx;
#pragma unroll
        for (int p = 0; p < 2; ++p) {
            float4 v = acc[p][dx];
            v.x *= sc; v.y *= sc; v.z *= sc; v.w *= sc;
            *(float4*)(ob + (size_t)k * HW + 4 * p) = v;
        }
    }
}

extern "C" void kernel_launch(void* const* d_in, const int* in_sizes, int n_in,
                              void* d_out, int out_size, void* d_ws, size_t ws_size,
                              hipStream_t stream) {
    const float* f1 = (const float*)d_in[0];
    const float* f2 = (const float*)d_in[1];
    float* out = (float*)d_out;
    // grid: 336 tiles x 3 dy-groups, swizzled so a tile's 3 blocks share an XCD
    costvol_kernel<<<dim3(1008), dim3(192), 0, stream>>>(f1, f2, out);
}